// Round 1
// baseline (294.176 us; speedup 1.0000x reference)
//
#include <hip/hip_runtime.h>
#include <math.h>

#define EQCAP 2048
#define PI_D 3.141592653589793

// ---------- helpers ----------
__device__ inline float wred_max(float v) {
    #pragma unroll
    for (int o = 32; o; o >>= 1) v = fmaxf(v, __shfl_xor(v, o));
    return v;
}
__device__ inline float wred_sum(float v) {
    #pragma unroll
    for (int o = 32; o; o >>= 1) v += __shfl_xor(v, o);
    return v;
}
__device__ inline unsigned fflip(float f) {
    unsigned b = __float_as_uint(f);
    return (b & 0x80000000u) ? ~b : (b | 0x80000000u);
}

// ---------- kernel 1: per-row KL loss (memory-bound, wave per row) ----------
// loss[m] = mean_w softmax(g)_w * (log_softmax(g)_w - log_softmax(p)_w)
__global__ __launch_bounds__(256) void k_loss(
    const float* __restrict__ px, const float* __restrict__ py,
    const float* __restrict__ gx, const float* __restrict__ gy,
    float* __restrict__ lossbuf, int M)
{
    int wid  = (blockIdx.x * blockDim.x + threadIdx.x) >> 6;
    int lane = threadIdx.x & 63;
    if (wid >= 2 * M) return;
    int ax  = wid >= M;
    int row = ax ? wid - M : wid;
    const float* p = ax ? py : px;
    const float* g = ax ? gy : gx;
    const float4* p4 = reinterpret_cast<const float4*>(p + (size_t)row * 512);
    const float4* g4 = reinterpret_cast<const float4*>(g + (size_t)row * 512);
    float4 pa = p4[lane], pb = p4[lane + 64];
    float4 ga = g4[lane], gb = g4[lane + 64];
    float pv[8] = {pa.x, pa.y, pa.z, pa.w, pb.x, pb.y, pb.z, pb.w};
    float gv[8] = {ga.x, ga.y, ga.z, ga.w, gb.x, gb.y, gb.z, gb.w};

    float mp = -INFINITY, mg = -INFINITY;
    #pragma unroll
    for (int i = 0; i < 8; i++) { mp = fmaxf(mp, pv[i]); mg = fmaxf(mg, gv[i]); }
    mp = wred_max(mp); mg = wred_max(mg);

    float sp = 0.f, sg = 0.f;
    #pragma unroll
    for (int i = 0; i < 8; i++) { sp += expf(pv[i] - mp); sg += expf(gv[i] - mg); }
    sp = wred_sum(sp); sg = wred_sum(sg);
    float lp = logf(sp), lg = logf(sg);

    float acc = 0.f;
    #pragma unroll
    for (int i = 0; i < 8; i++) {
        float lsg = (gv[i] - mg) - lg;      // log_softmax(gt)
        float lsp = (pv[i] - mp) - lp;      // log_softmax(pred)
        acc += expf(lsg) * (lsg - lsp);
    }
    acc = wred_sum(acc);
    if (lane == 0) lossbuf[wid] = acc * (1.0f / 512.0f);
}

// ---------- kernel 2: stats (count_nonzero -> k, per-axis max, flipped keys) ----------
__global__ __launch_bounds__(256) void k_stats(
    const float* __restrict__ tw, const int* __restrict__ ep,
    const float* __restrict__ lossbuf, unsigned* __restrict__ ubuf,
    double* __restrict__ acc, int* __restrict__ ki,
    float* __restrict__ gmaxp, int* __restrict__ eqc, int M)
{
    __shared__ float s_red[8];
    __shared__ int   s_cnt[4];
    __shared__ float s_gm[2];
    int tid = threadIdx.x, lane = tid & 63, wv = tid >> 6;

    int cnt = 0; float mx = -INFINITY, my = -INFINITY;
    for (int j = tid; j < M; j += 256) {
        cnt += (tw[j] != 0.0f);
        mx = fmaxf(mx, lossbuf[j]);
        my = fmaxf(my, lossbuf[M + j]);
    }
    #pragma unroll
    for (int o = 32; o; o >>= 1) {
        cnt += __shfl_xor(cnt, o);
        mx = fmaxf(mx, __shfl_xor(mx, o));
        my = fmaxf(my, __shfl_xor(my, o));
    }
    if (lane == 0) { s_red[wv] = mx; s_red[4 + wv] = my; s_cnt[wv] = cnt; }
    __syncthreads();
    if (tid == 0) {
        float gx_ = fmaxf(fmaxf(s_red[0], s_red[1]), fmaxf(s_red[2], s_red[3]));
        float gy_ = fmaxf(fmaxf(s_red[4], s_red[5]), fmaxf(s_red[6], s_red[7]));
        int c = s_cnt[0] + s_cnt[1] + s_cnt[2] + s_cnt[3];
        // rate(epoch): cosine rampdown, clipped to [0.8, 1.0], double math like numpy
        double cur = (double)(ep[0] - 210);
        cur = fmin(fmax(cur, 0.0), 30.0);
        double r = 0.5 * (cos(PI_D * cur / 30.0) + 1.0);
        r = fmin(fmax(r, 0.8), 1.0);
        *ki = (int)((double)c * r);     // truncation matches Python int()
        gmaxp[0] = gx_; gmaxp[1] = gy_;
        *acc = 0.0;
        eqc[0] = 0; eqc[1] = 0;
        s_gm[0] = gx_; s_gm[1] = gy_;
    }
    __syncthreads();
    float g0 = s_gm[0], g1 = s_gm[1];
    // loss_new = tw>0 ? loss : gmax, stored as order-preserving flipped uint
    for (int j = tid; j < M; j += 256) {
        float tv = tw[j];
        float vx = (tv > 0.f) ? lossbuf[j]     : g0;
        float vy = (tv > 0.f) ? lossbuf[M + j] : g1;
        ubuf[j]     = fflip(vx);
        ubuf[M + j] = fflip(vy);
    }
}

// ---------- kernel 3: 4-pass radix select of k-th smallest (per axis) ----------
__global__ __launch_bounds__(256) void k_select(
    const unsigned* __restrict__ ubuf, const int* __restrict__ ki,
    unsigned* __restrict__ thr_u, int* __restrict__ cless, int M)
{
    int ax = blockIdx.x;
    const unsigned* u = ubuf + (size_t)ax * M;
    __shared__ int hist[256];
    __shared__ unsigned s_pref;
    __shared__ int s_kr, s_cl;
    int tid = threadIdx.x;
    int k = *ki;
    if (k <= 0) { if (tid == 0) { thr_u[ax] = 0u; cless[ax] = 0; } return; }
    if (tid == 0) { s_pref = 0u; s_kr = k; s_cl = 0; }
    const unsigned mhi[4] = {0x00000000u, 0xFF000000u, 0xFFFF0000u, 0xFFFFFF00u};
    for (int pass = 0; pass < 4; ++pass) {
        int shift = 24 - 8 * pass;
        __syncthreads();
        hist[tid] = 0;
        __syncthreads();
        unsigned m = mhi[pass];
        unsigned pref = s_pref;
        for (int j = tid; j < M; j += 256) {
            unsigned v = u[j];
            if ((v & m) == (pref & m)) atomicAdd(&hist[(v >> shift) & 255], 1);
        }
        __syncthreads();
        if (tid == 0) {
            int cum = 0;
            for (int b = 0; b < 256; b++) {
                int h = hist[b];
                if (cum + h >= s_kr) { s_pref |= ((unsigned)b) << shift; s_kr -= cum; s_cl += cum; break; }
                cum += h;
            }
        }
    }
    __syncthreads();
    if (tid == 0) { thr_u[ax] = s_pref; cless[ax] = s_cl; }
}

// ---------- kernel 4: weights + masked dot partials ----------
__global__ __launch_bounds__(256) void k_weight(
    const float* __restrict__ tw, const int* __restrict__ ul,
    const float* __restrict__ lossbuf, const unsigned* __restrict__ ubuf,
    float* __restrict__ outw, const int* __restrict__ ki,
    const unsigned* __restrict__ thr_u, int* __restrict__ eqc,
    int* __restrict__ eqlist, double* __restrict__ acc, int M, int Kj)
{
    int ax = blockIdx.y;
    int m = blockIdx.x * blockDim.x + threadIdx.x;
    double contrib = 0.0;
    if (m < M) {
        int k = *ki;
        float mask = 0.f;
        unsigned v = ubuf[(size_t)ax * M + m];
        unsigned t = thr_u[ax];
        if (k > 0) {
            if (v < t) mask = 1.f;
            else if (v == t) {
                int pos = atomicAdd(&eqc[ax], 1);
                if (pos < EQCAP) eqlist[ax * EQCAP + pos] = m;
            }
        }
        float wr = (ul[m / Kj] == 0) ? tw[m] : 0.f;   // weight_real
        float wall = 2.f * wr + mask;
        outw[(size_t)ax * M + m] = wall;
        contrib = (double)lossbuf[(size_t)ax * M + m] * (double)wall;
    }
    #pragma unroll
    for (int o = 32; o; o >>= 1) contrib += __shfl_xor(contrib, o);
    __shared__ double s_c[4];
    int lane = threadIdx.x & 63, wv = threadIdx.x >> 6;
    if (lane == 0) s_c[wv] = contrib;
    __syncthreads();
    if (threadIdx.x == 0) atomicAdd(acc, s_c[0] + s_c[1] + s_c[2] + s_c[3]);
}

// ---------- kernel 5: tie fixup (lowest-index semantics) + final scalar ----------
__global__ __launch_bounds__(256) void k_fix(
    float* __restrict__ outw, float* __restrict__ out0,
    const float* __restrict__ lossbuf, const int* __restrict__ ki,
    const int* __restrict__ cless, const int* __restrict__ eqc,
    const int* __restrict__ eqlist, const double* __restrict__ acc, int M, int Kj)
{
    __shared__ double s_c[4];
    int tid = threadIdx.x;
    double extra = 0.0;
    for (int ax = 0; ax < 2; ++ax) {
        int k = *ki;
        int ec = eqc[ax]; if (ec > EQCAP) ec = EQCAP;
        int need = (k > 0) ? (k - cless[ax]) : 0;
        if (need < 0) need = 0;
        if (need > ec) need = ec;
        if (need == ec) {
            for (int i = tid; i < ec; i += 256) {
                int m = eqlist[ax * EQCAP + i];
                outw[(size_t)ax * M + m] += 1.f;
                extra += (double)lossbuf[(size_t)ax * M + m];
            }
        } else if (tid == 0) {
            // pick `need` lowest indices among equals (top_k tie semantics)
            int last = -1;
            for (int s = 0; s < need; ++s) {
                int best = 0x7fffffff;
                for (int i = 0; i < ec; i++) {
                    int v = eqlist[ax * EQCAP + i];
                    if (v > last && v < best) best = v;
                }
                last = best;
                outw[(size_t)ax * M + best] += 1.f;
                extra += (double)lossbuf[(size_t)ax * M + best];
            }
        }
        __syncthreads();
    }
    #pragma unroll
    for (int o = 32; o; o >>= 1) extra += __shfl_xor(extra, o);
    int lane = tid & 63, wv = tid >> 6;
    if (lane == 0) s_c[wv] = extra;
    __syncthreads();
    if (tid == 0)
        out0[0] = (float)((acc[0] + s_c[0] + s_c[1] + s_c[2] + s_c[3]) / (double)Kj);
}

extern "C" void kernel_launch(void* const* d_in, const int* in_sizes, int n_in,
                              void* d_out, int out_size, void* d_ws, size_t ws_size,
                              hipStream_t stream)
{
    const float* px = (const float*)d_in[0];
    const float* py = (const float*)d_in[1];
    const float* gx = (const float*)d_in[2];
    const float* gy = (const float*)d_in[3];
    const float* tw = (const float*)d_in[4];
    const int*   ul = (const int*)d_in[5];
    const int*   ep = (const int*)d_in[6];

    int M  = in_sizes[4];        // N*K = 17408
    int N  = in_sizes[5];        // 1024
    int Kj = M / N;              // 17
    // W assumed 512 (in_sizes[0]/M) — k_loss hardcodes the float4 layout

    float* out  = (float*)d_out;
    float* out0 = out;           // scalar loss
    float* outw = out + 1;       // [2*M] weights (x then y)

    char* ws = (char*)d_ws;
    double*   acc     = (double*)(ws + 0);
    int*      ki      = (int*)(ws + 8);
    float*    gmaxp   = (float*)(ws + 16);
    unsigned* thr_u   = (unsigned*)(ws + 24);
    int*      cless   = (int*)(ws + 32);
    int*      eqc     = (int*)(ws + 40);
    float*    lossbuf = (float*)(ws + 64);
    unsigned* ubuf    = (unsigned*)(ws + 64 + (size_t)8 * M);
    int*      eqlist  = (int*)(ws + 64 + (size_t)16 * M);

    // 1: per-row losses (wave per row, 4 waves/block)
    int nwaves = 2 * M;
    int blocks = (nwaves + 3) / 4;
    k_loss<<<blocks, 256, 0, stream>>>(px, py, gx, gy, lossbuf, M);

    // 2: k, per-axis max, flipped keys (also zeroes acc/eq counters)
    k_stats<<<1, 256, 0, stream>>>(tw, ep, lossbuf, ubuf, acc, ki, gmaxp, eqc, M);

    // 3: radix select threshold per axis
    k_select<<<2, 256, 0, stream>>>(ubuf, ki, thr_u, cless, M);

    // 4: weights + dot partials
    dim3 g4((M + 255) / 256, 2);
    k_weight<<<g4, 256, 0, stream>>>(tw, ul, lossbuf, ubuf, outw, ki, thr_u,
                                     eqc, eqlist, acc, M, Kj);

    // 5: tie fixup + final scalar
    k_fix<<<1, 256, 0, stream>>>(outw, out0, lossbuf, ki, cless, eqc, eqlist, acc, M, Kj);
}

// Round 3
// 268.849 us; speedup vs baseline: 1.0942x; 1.0942x over previous
//
#include <hip/hip_runtime.h>
#include <math.h>

#define EQCAP 2048
#define PI_D 3.141592653589793

// ---------- helpers ----------
__device__ inline float wred_max(float v) {
    #pragma unroll
    for (int o = 32; o; o >>= 1) v = fmaxf(v, __shfl_xor(v, o));
    return v;
}
__device__ inline float wred_sum(float v) {
    #pragma unroll
    for (int o = 32; o; o >>= 1) v += __shfl_xor(v, o);
    return v;
}
__device__ inline unsigned fflip(float f) {
    unsigned b = __float_as_uint(f);
    return (b & 0x80000000u) ? ~b : (b | 0x80000000u);
}

// ---------- kernel 0: zero the scalar workspace slots ----------
__global__ void k_init(double* acc, int* count, unsigned* gmax_u, int* eqc) {
    if (threadIdx.x == 0) {
        *acc = 0.0; *count = 0;
        gmax_u[0] = 0u; gmax_u[1] = 0u;
        eqc[0] = 0; eqc[1] = 0;
    }
}

// ---------- kernel 1: per-row KL loss (memory-bound, wave per row) ----------
__global__ __launch_bounds__(256) void k_loss(
    const float* __restrict__ px, const float* __restrict__ py,
    const float* __restrict__ gx, const float* __restrict__ gy,
    float* __restrict__ lossbuf, int M)
{
    int wid  = (blockIdx.x * blockDim.x + threadIdx.x) >> 6;
    int lane = threadIdx.x & 63;
    if (wid >= 2 * M) return;
    int ax  = wid >= M;
    int row = ax ? wid - M : wid;
    const float* p = ax ? py : px;
    const float* g = ax ? gy : gx;
    const float4* p4 = reinterpret_cast<const float4*>(p + (size_t)row * 512);
    const float4* g4 = reinterpret_cast<const float4*>(g + (size_t)row * 512);
    float4 pa = p4[lane], pb = p4[lane + 64];
    float4 ga = g4[lane], gb = g4[lane + 64];
    float pv[8] = {pa.x, pa.y, pa.z, pa.w, pb.x, pb.y, pb.z, pb.w};
    float gv[8] = {ga.x, ga.y, ga.z, ga.w, gb.x, gb.y, gb.z, gb.w};

    float mp = -INFINITY, mg = -INFINITY;
    #pragma unroll
    for (int i = 0; i < 8; i++) { mp = fmaxf(mp, pv[i]); mg = fmaxf(mg, gv[i]); }
    mp = wred_max(mp); mg = wred_max(mg);

    float sp = 0.f, sg = 0.f;
    #pragma unroll
    for (int i = 0; i < 8; i++) { sp += expf(pv[i] - mp); sg += expf(gv[i] - mg); }
    sp = wred_sum(sp); sg = wred_sum(sg);
    float lp = logf(sp), lg = logf(sg);

    float acc = 0.f;
    #pragma unroll
    for (int i = 0; i < 8; i++) {
        float lsg = (gv[i] - mg) - lg;      // log_softmax(gt)
        float lsp = (pv[i] - mp) - lp;      // log_softmax(pred)
        acc += expf(lsg) * (lsg - lsp);
    }
    acc = wred_sum(acc);
    if (lane == 0) lossbuf[wid] = acc * (1.0f / 512.0f);
}

// ---------- kernel 2: multi-block stats: count_nonzero(tw), per-axis max ----------
__global__ __launch_bounds__(256) void k_stats2(
    const float* __restrict__ tw, const float* __restrict__ lossbuf,
    int* __restrict__ count, unsigned* __restrict__ gmax_u, int M)
{
    int tid = threadIdx.x, lane = tid & 63, wv = tid >> 6;
    int j = blockIdx.x * 256 + tid;
    int c = 0; unsigned ux = 0u, uy = 0u;
    if (j < M) {
        c  = (tw[j] != 0.0f);
        ux = fflip(lossbuf[j]);
        uy = fflip(lossbuf[M + j]);
    }
    #pragma unroll
    for (int o = 32; o; o >>= 1) {
        c += __shfl_xor(c, o);
        ux = max(ux, (unsigned)__shfl_xor((int)ux, o));
        uy = max(uy, (unsigned)__shfl_xor((int)uy, o));
    }
    __shared__ int sc[4]; __shared__ unsigned sx[4], sy[4];
    if (lane == 0) { sc[wv] = c; sx[wv] = ux; sy[wv] = uy; }
    __syncthreads();
    if (tid == 0) {
        int cs = sc[0] + sc[1] + sc[2] + sc[3];
        unsigned xs = max(max(sx[0], sx[1]), max(sx[2], sx[3]));
        unsigned ys = max(max(sy[0], sy[1]), max(sy[2], sy[3]));
        if (cs) atomicAdd(count, cs);
        atomicMax(&gmax_u[0], xs);
        atomicMax(&gmax_u[1], ys);
    }
}

// ---------- kernel 3: 4-pass radix select, parallel bucket choose ----------
__global__ __launch_bounds__(256) void k_select(
    const float* __restrict__ tw, const float* __restrict__ lossbuf,
    const int* __restrict__ count, const unsigned* __restrict__ gmax_u,
    const int* __restrict__ ep,
    int* __restrict__ ki, unsigned* __restrict__ thr_u, int* __restrict__ cless, int M)
{
    int ax = blockIdx.x;
    int tid = threadIdx.x, lane = tid & 63, wv = tid >> 6;
    __shared__ int hist[256];
    __shared__ unsigned s_pref;
    __shared__ int s_kr, s_cl;
    __shared__ int wsum[4];

    if (tid == 0) {
        int c = *count;
        double cur = fmin(fmax((double)(ep[0] - 210), 0.0), 30.0);
        double r = 0.5 * (cos(PI_D * cur / 30.0) + 1.0);
        r = fmin(fmax(r, 0.8), 1.0);
        int k = (int)((double)c * r);    // truncation matches Python int()
        s_kr = k; s_pref = 0u; s_cl = 0;
        if (ax == 0) *ki = k;
    }
    __syncthreads();
    int k0 = s_kr;
    if (k0 <= 0) { if (tid == 0) { thr_u[ax] = 0u; cless[ax] = 0; } return; }

    unsigned gmu = gmax_u[ax];
    const float* lb = lossbuf + (size_t)ax * M;
    const unsigned mhi[4] = {0x00000000u, 0xFF000000u, 0xFFFF0000u, 0xFFFFFF00u};

    for (int pass = 0; pass < 4; ++pass) {
        int shift = 24 - 8 * pass;
        hist[tid] = 0;
        __syncthreads();
        unsigned m = mhi[pass];
        unsigned pref = s_pref;
        for (int j = tid; j < M; j += 256) {
            unsigned v = (tw[j] > 0.f) ? fflip(lb[j]) : gmu;
            if ((v & m) == (pref & m)) atomicAdd(&hist[(v >> shift) & 255], 1);
        }
        __syncthreads();
        int kr = s_kr;                 // read before anyone can write it
        int h = hist[tid];
        int inc = h;
        #pragma unroll
        for (int o = 1; o < 64; o <<= 1) {
            int n = __shfl_up(inc, o);
            if (lane >= o) inc += n;
        }
        if (lane == 63) wsum[wv] = inc;
        __syncthreads();               // separates s_kr read from the write below
        int off = 0;
        #pragma unroll
        for (int w = 0; w < 4; w++) if (w < wv) off += wsum[w];
        int incl = inc + off, excl = incl - h;
        if (excl < kr && incl >= kr) { // exactly one thread
            s_pref |= ((unsigned)tid) << shift;
            s_kr = kr - excl;
            s_cl += excl;
        }
        __syncthreads();
    }
    if (tid == 0) { thr_u[ax] = s_pref; cless[ax] = s_cl; }
}

// ---------- kernel 4: weights + masked dot partials ----------
__global__ __launch_bounds__(256) void k_weight(
    const float* __restrict__ tw, const int* __restrict__ ul,
    const float* __restrict__ lossbuf, const unsigned* __restrict__ gmax_u,
    float* __restrict__ outw, const int* __restrict__ ki,
    const unsigned* __restrict__ thr_u, int* __restrict__ eqc,
    int* __restrict__ eqlist, double* __restrict__ acc, int M, int Kj)
{
    int ax = blockIdx.y;
    int m = blockIdx.x * blockDim.x + threadIdx.x;
    double contrib = 0.0;
    if (m < M) {
        int k = *ki;
        float mask = 0.f;
        unsigned v = (tw[m] > 0.f) ? fflip(lossbuf[(size_t)ax * M + m]) : gmax_u[ax];
        unsigned t = thr_u[ax];
        if (k > 0) {
            if (v < t) mask = 1.f;
            else if (v == t) {
                int pos = atomicAdd(&eqc[ax], 1);
                if (pos < EQCAP) eqlist[ax * EQCAP + pos] = m;
            }
        }
        float wr = (ul[m / Kj] == 0) ? tw[m] : 0.f;   // weight_real
        float wall = 2.f * wr + mask;
        outw[(size_t)ax * M + m] = wall;
        contrib = (double)lossbuf[(size_t)ax * M + m] * (double)wall;
    }
    #pragma unroll
    for (int o = 32; o; o >>= 1) contrib += __shfl_xor(contrib, o);
    __shared__ double s_c[4];
    int lane = threadIdx.x & 63, wv = threadIdx.x >> 6;
    if (lane == 0) s_c[wv] = contrib;
    __syncthreads();
    if (threadIdx.x == 0) atomicAdd(acc, s_c[0] + s_c[1] + s_c[2] + s_c[3]);
}

// ---------- kernel 5: tie fixup (lowest-index semantics) + final scalar ----------
__global__ __launch_bounds__(256) void k_fix(
    float* __restrict__ outw, float* __restrict__ out0,
    const float* __restrict__ lossbuf, const int* __restrict__ ki,
    const int* __restrict__ cless, const int* __restrict__ eqc,
    const int* __restrict__ eqlist, const double* __restrict__ acc, int M, int Kj)
{
    __shared__ double s_c[4];
    int tid = threadIdx.x;
    double extra = 0.0;
    for (int ax = 0; ax < 2; ++ax) {
        int k = *ki;
        int ec = eqc[ax]; if (ec > EQCAP) ec = EQCAP;
        int need = (k > 0) ? (k - cless[ax]) : 0;
        if (need < 0) need = 0;
        if (need > ec) need = ec;
        if (need == ec) {
            for (int i = tid; i < ec; i += 256) {
                int m = eqlist[ax * EQCAP + i];
                outw[(size_t)ax * M + m] += 1.f;
                extra += (double)lossbuf[(size_t)ax * M + m];
            }
        } else if (tid == 0) {
            // pick `need` lowest indices among equals (top_k tie semantics)
            int last = -1;
            for (int s = 0; s < need; ++s) {
                int best = 0x7fffffff;
                for (int i = 0; i < ec; i++) {
                    int v = eqlist[ax * EQCAP + i];
                    if (v > last && v < best) best = v;
                }
                last = best;
                outw[(size_t)ax * M + best] += 1.f;
                extra += (double)lossbuf[(size_t)ax * M + best];
            }
        }
        __syncthreads();
    }
    #pragma unroll
    for (int o = 32; o; o >>= 1) extra += __shfl_xor(extra, o);
    int lane = tid & 63, wv = tid >> 6;
    if (lane == 0) s_c[wv] = extra;
    __syncthreads();
    if (tid == 0)
        out0[0] = (float)((acc[0] + s_c[0] + s_c[1] + s_c[2] + s_c[3]) / (double)Kj);
}

extern "C" void kernel_launch(void* const* d_in, const int* in_sizes, int n_in,
                              void* d_out, int out_size, void* d_ws, size_t ws_size,
                              hipStream_t stream)
{
    const float* px = (const float*)d_in[0];
    const float* py = (const float*)d_in[1];
    const float* gx = (const float*)d_in[2];
    const float* gy = (const float*)d_in[3];
    const float* tw = (const float*)d_in[4];
    const int*   ul = (const int*)d_in[5];
    const int*   ep = (const int*)d_in[6];

    int M  = in_sizes[4];        // N*K = 17408
    int N  = in_sizes[5];        // 1024
    int Kj = M / N;              // 17

    float* out  = (float*)d_out;
    float* out0 = out;           // scalar loss
    float* outw = out + 1;       // [2*M] weights (x then y)

    char* ws = (char*)d_ws;
    double*   acc     = (double*)(ws + 0);
    int*      ki      = (int*)(ws + 8);
    int*      count   = (int*)(ws + 12);
    unsigned* gmax_u  = (unsigned*)(ws + 16);
    unsigned* thr_u   = (unsigned*)(ws + 24);
    int*      cless   = (int*)(ws + 32);
    int*      eqc     = (int*)(ws + 40);
    float*    lossbuf = (float*)(ws + 64);
    int*      eqlist  = (int*)(ws + 64 + (size_t)8 * M);

    k_init<<<1, 64, 0, stream>>>(acc, count, gmax_u, eqc);

    // per-row losses (wave per row, 4 waves/block)
    int nwaves = 2 * M;
    k_loss<<<(nwaves + 3) / 4, 256, 0, stream>>>(px, py, gx, gy, lossbuf, M);

    // multi-block count + per-axis max
    k_stats2<<<(M + 255) / 256, 256, 0, stream>>>(tw, lossbuf, count, gmax_u, M);

    // radix select threshold per axis (keys computed on the fly)
    k_select<<<2, 256, 0, stream>>>(tw, lossbuf, count, gmax_u, ep, ki, thr_u, cless, M);

    // weights + dot partials
    dim3 g4((M + 255) / 256, 2);
    k_weight<<<g4, 256, 0, stream>>>(tw, ul, lossbuf, gmax_u, outw, ki, thr_u,
                                     eqc, eqlist, acc, M, Kj);

    // tie fixup + final scalar
    k_fix<<<1, 256, 0, stream>>>(outw, out0, lossbuf, ki, cless, eqc, eqlist, acc, M, Kj);
}

// Round 7
// 208.284 us; speedup vs baseline: 1.4124x; 1.2908x over previous
//
#include <hip/hip_runtime.h>
#include <math.h>

#define EQCAP 2048
#define PI_D 3.141592653589793

// ---------- helpers ----------
__device__ inline float wred_max(float v) {
    #pragma unroll
    for (int o = 32; o; o >>= 1) v = fmaxf(v, __shfl_xor(v, o));
    return v;
}
__device__ inline float wred_sum(float v) {
    #pragma unroll
    for (int o = 32; o; o >>= 1) v += __shfl_xor(v, o);
    return v;
}
__device__ inline unsigned fflip(float f) {
    unsigned b = __float_as_uint(f);
    return (b & 0x80000000u) ? ~b : (b | 0x80000000u);
}

// ---------- kernel 0: zero the scalar workspace slots ----------
__global__ void k_init(double* acc, int* count, unsigned* gmax_u, int* eqc) {
    if (threadIdx.x == 0) {
        *acc = 0.0; *count = 0;
        gmax_u[0] = 0u; gmax_u[1] = 0u;
        eqc[0] = 0; eqc[1] = 0;
    }
}

// ---------- kernel 1: per-row KL loss (memory-bound, wave per row) ----------
__global__ __launch_bounds__(256) void k_loss(
    const float* __restrict__ px, const float* __restrict__ py,
    const float* __restrict__ gx, const float* __restrict__ gy,
    float* __restrict__ lossbuf, int M)
{
    int wid  = (blockIdx.x * blockDim.x + threadIdx.x) >> 6;
    int lane = threadIdx.x & 63;
    if (wid >= 2 * M) return;
    int ax  = wid >= M;
    int row = ax ? wid - M : wid;
    const float* p = ax ? py : px;
    const float* g = ax ? gy : gx;
    const float4* p4 = reinterpret_cast<const float4*>(p + (size_t)row * 512);
    const float4* g4 = reinterpret_cast<const float4*>(g + (size_t)row * 512);
    float4 pa = p4[lane], pb = p4[lane + 64];
    float4 ga = g4[lane], gb = g4[lane + 64];
    float pv[8] = {pa.x, pa.y, pa.z, pa.w, pb.x, pb.y, pb.z, pb.w};
    float gv[8] = {ga.x, ga.y, ga.z, ga.w, gb.x, gb.y, gb.z, gb.w};

    float mp = -INFINITY, mg = -INFINITY;
    #pragma unroll
    for (int i = 0; i < 8; i++) { mp = fmaxf(mp, pv[i]); mg = fmaxf(mg, gv[i]); }
    mp = wred_max(mp); mg = wred_max(mg);

    float sp = 0.f, sg = 0.f;
    #pragma unroll
    for (int i = 0; i < 8; i++) { sp += expf(pv[i] - mp); sg += expf(gv[i] - mg); }
    sp = wred_sum(sp); sg = wred_sum(sg);
    float lp = logf(sp), lg = logf(sg);

    float acc = 0.f;
    #pragma unroll
    for (int i = 0; i < 8; i++) {
        float lsg = (gv[i] - mg) - lg;      // log_softmax(gt)
        float lsp = (pv[i] - mp) - lp;      // log_softmax(pred)
        acc += expf(lsg) * (lsg - lsp);
    }
    acc = wred_sum(acc);
    if (lane == 0) lossbuf[wid] = acc * (1.0f / 512.0f);
}

// ---------- kernel 2: multi-block stats: count_nonzero(tw), per-axis max ----------
__global__ __launch_bounds__(256) void k_stats2(
    const float* __restrict__ tw, const float* __restrict__ lossbuf,
    int* __restrict__ count, unsigned* __restrict__ gmax_u, int M)
{
    int tid = threadIdx.x, lane = tid & 63, wv = tid >> 6;
    int j = blockIdx.x * 256 + tid;
    int c = 0; unsigned ux = 0u, uy = 0u;
    if (j < M) {
        c  = (tw[j] != 0.0f);
        ux = fflip(lossbuf[j]);
        uy = fflip(lossbuf[M + j]);
    }
    #pragma unroll
    for (int o = 32; o; o >>= 1) {
        c += __shfl_xor(c, o);
        ux = max(ux, (unsigned)__shfl_xor((int)ux, o));
        uy = max(uy, (unsigned)__shfl_xor((int)uy, o));
    }
    __shared__ int sc[4]; __shared__ unsigned sx[4], sy[4];
    if (lane == 0) { sc[wv] = c; sx[wv] = ux; sy[wv] = uy; }
    __syncthreads();
    if (tid == 0) {
        int cs = sc[0] + sc[1] + sc[2] + sc[3];
        unsigned xs = max(max(sx[0], sx[1]), max(sx[2], sx[3]));
        unsigned ys = max(max(sy[0], sy[1]), max(sy[2], sy[3]));
        if (cs) atomicAdd(count, cs);
        atomicMax(&gmax_u[0], xs);
        atomicMax(&gmax_u[1], ys);
    }
}

// ---------- kernel 3: radix select — stage keys in LDS once, 4 passes from LDS ----------
// 1024 threads/block, one block per axis. Global data is touched exactly once.
__global__ __launch_bounds__(1024) void k_select(
    const float* __restrict__ tw, const float* __restrict__ lossbuf,
    const int* __restrict__ count, const unsigned* __restrict__ gmax_u,
    const int* __restrict__ ep,
    int* __restrict__ ki, unsigned* __restrict__ thr_u, int* __restrict__ cless, int M)
{
    extern __shared__ unsigned keys[];      // M unsigned keys (68 KB for M=17408)
    int ax = blockIdx.x;
    int tid = threadIdx.x, lane = tid & 63, wv = tid >> 6;
    __shared__ int hist[256];
    __shared__ unsigned s_pref;
    __shared__ int s_kr, s_cl;
    __shared__ int wsum[4];

    if (tid == 0) {
        int c = *count;
        double cur = fmin(fmax((double)(ep[0] - 210), 0.0), 30.0);
        double r = 0.5 * (cos(PI_D * cur / 30.0) + 1.0);
        r = fmin(fmax(r, 0.8), 1.0);
        int k = (int)((double)c * r);    // truncation matches Python int()
        s_kr = k; s_pref = 0u; s_cl = 0;
        if (ax == 0) *ki = k;
    }

    // stage keys: independent loads, fully pipelined; one global pass total
    unsigned gmu = gmax_u[ax];
    const float* lb = lossbuf + (size_t)ax * M;
    for (int j = tid; j < M; j += 1024) {
        float t = tw[j];
        float l = lb[j];
        keys[j] = (t > 0.f) ? fflip(l) : gmu;
    }
    __syncthreads();

    int k0 = s_kr;
    if (k0 <= 0) { if (tid == 0) { thr_u[ax] = 0u; cless[ax] = 0; } return; }

    const unsigned mhi[4] = {0x00000000u, 0xFF000000u, 0xFFFF0000u, 0xFFFFFF00u};

    for (int pass = 0; pass < 4; ++pass) {
        int shift = 24 - 8 * pass;
        if (tid < 256) hist[tid] = 0;
        __syncthreads();
        unsigned m = mhi[pass];
        unsigned pref = s_pref;
        for (int j = tid; j < M; j += 1024) {
            unsigned v = keys[j];
            if ((v & m) == (pref & m)) atomicAdd(&hist[(v >> shift) & 255], 1);
        }
        __syncthreads();
        int kr = s_kr;                 // read before anyone can write it
        int h = (tid < 256) ? hist[tid] : 0;
        int inc = h;
        #pragma unroll
        for (int o = 1; o < 64; o <<= 1) {
            int n = __shfl_up(inc, o);
            if (lane >= o) inc += n;
        }
        if (lane == 63 && wv < 4) wsum[wv] = inc;
        __syncthreads();               // separates s_kr read from the write below
        if (tid < 256) {
            int off = 0;
            #pragma unroll
            for (int w = 0; w < 4; w++) if (w < wv) off += wsum[w];
            int incl = inc + off, excl = incl - h;
            if (excl < kr && incl >= kr) { // exactly one thread
                s_pref |= ((unsigned)tid) << shift;
                s_kr = kr - excl;
                s_cl += excl;
            }
        }
        __syncthreads();
    }
    if (tid == 0) { thr_u[ax] = s_pref; cless[ax] = s_cl; }
}

// ---------- kernel 4: weights + masked dot partials ----------
__global__ __launch_bounds__(256) void k_weight(
    const float* __restrict__ tw, const int* __restrict__ ul,
    const float* __restrict__ lossbuf, const unsigned* __restrict__ gmax_u,
    float* __restrict__ outw, const int* __restrict__ ki,
    const unsigned* __restrict__ thr_u, int* __restrict__ eqc,
    int* __restrict__ eqlist, double* __restrict__ acc, int M, int Kj)
{
    int ax = blockIdx.y;
    int m = blockIdx.x * blockDim.x + threadIdx.x;
    double contrib = 0.0;
    if (m < M) {
        int k = *ki;
        float mask = 0.f;
        unsigned v = (tw[m] > 0.f) ? fflip(lossbuf[(size_t)ax * M + m]) : gmax_u[ax];
        unsigned t = thr_u[ax];
        if (k > 0) {
            if (v < t) mask = 1.f;
            else if (v == t) {
                int pos = atomicAdd(&eqc[ax], 1);
                if (pos < EQCAP) eqlist[ax * EQCAP + pos] = m;
            }
        }
        float wr = (ul[m / Kj] == 0) ? tw[m] : 0.f;   // weight_real
        float wall = 2.f * wr + mask;
        outw[(size_t)ax * M + m] = wall;
        contrib = (double)lossbuf[(size_t)ax * M + m] * (double)wall;
    }
    #pragma unroll
    for (int o = 32; o; o >>= 1) contrib += __shfl_xor(contrib, o);
    __shared__ double s_c[4];
    int lane = threadIdx.x & 63, wv = threadIdx.x >> 6;
    if (lane == 0) s_c[wv] = contrib;
    __syncthreads();
    if (threadIdx.x == 0) atomicAdd(acc, s_c[0] + s_c[1] + s_c[2] + s_c[3]);
}

// ---------- kernel 5: tie fixup (lowest-index semantics) + final scalar ----------
__global__ __launch_bounds__(256) void k_fix(
    float* __restrict__ outw, float* __restrict__ out0,
    const float* __restrict__ lossbuf, const int* __restrict__ ki,
    const int* __restrict__ cless, const int* __restrict__ eqc,
    const int* __restrict__ eqlist, const double* __restrict__ acc, int M, int Kj)
{
    __shared__ double s_c[4];
    int tid = threadIdx.x;
    double extra = 0.0;
    for (int ax = 0; ax < 2; ++ax) {
        int k = *ki;
        int ec = eqc[ax]; if (ec > EQCAP) ec = EQCAP;
        int need = (k > 0) ? (k - cless[ax]) : 0;
        if (need < 0) need = 0;
        if (need > ec) need = ec;
        if (need == ec) {
            for (int i = tid; i < ec; i += 256) {
                int m = eqlist[ax * EQCAP + i];
                outw[(size_t)ax * M + m] += 1.f;
                extra += (double)lossbuf[(size_t)ax * M + m];
            }
        } else if (tid == 0) {
            // pick `need` lowest indices among equals (top_k tie semantics)
            int last = -1;
            for (int s = 0; s < need; ++s) {
                int best = 0x7fffffff;
                for (int i = 0; i < ec; i++) {
                    int v = eqlist[ax * EQCAP + i];
                    if (v > last && v < best) best = v;
                }
                last = best;
                outw[(size_t)ax * M + best] += 1.f;
                extra += (double)lossbuf[(size_t)ax * M + best];
            }
        }
        __syncthreads();
    }
    #pragma unroll
    for (int o = 32; o; o >>= 1) extra += __shfl_xor(extra, o);
    int lane = tid & 63, wv = tid >> 6;
    if (lane == 0) s_c[wv] = extra;
    __syncthreads();
    if (tid == 0)
        out0[0] = (float)((acc[0] + s_c[0] + s_c[1] + s_c[2] + s_c[3]) / (double)Kj);
}

extern "C" void kernel_launch(void* const* d_in, const int* in_sizes, int n_in,
                              void* d_out, int out_size, void* d_ws, size_t ws_size,
                              hipStream_t stream)
{
    const float* px = (const float*)d_in[0];
    const float* py = (const float*)d_in[1];
    const float* gx = (const float*)d_in[2];
    const float* gy = (const float*)d_in[3];
    const float* tw = (const float*)d_in[4];
    const int*   ul = (const int*)d_in[5];
    const int*   ep = (const int*)d_in[6];

    int M  = in_sizes[4];        // N*K = 17408
    int N  = in_sizes[5];        // 1024
    int Kj = M / N;              // 17

    float* out  = (float*)d_out;
    float* out0 = out;           // scalar loss
    float* outw = out + 1;       // [2*M] weights (x then y)

    char* ws = (char*)d_ws;
    double*   acc     = (double*)(ws + 0);
    int*      ki      = (int*)(ws + 8);
    int*      count   = (int*)(ws + 12);
    unsigned* gmax_u  = (unsigned*)(ws + 16);
    unsigned* thr_u   = (unsigned*)(ws + 24);
    int*      cless   = (int*)(ws + 32);
    int*      eqc     = (int*)(ws + 40);
    float*    lossbuf = (float*)(ws + 64);
    int*      eqlist  = (int*)(ws + 64 + (size_t)8 * M);

    k_init<<<1, 64, 0, stream>>>(acc, count, gmax_u, eqc);

    // per-row losses (wave per row, 4 waves/block)
    int nwaves = 2 * M;
    k_loss<<<(nwaves + 3) / 4, 256, 0, stream>>>(px, py, gx, gy, lossbuf, M);

    // multi-block count + per-axis max
    k_stats2<<<(M + 255) / 256, 256, 0, stream>>>(tw, lossbuf, count, gmax_u, M);

    // radix select: stage keys in LDS (dynamic, M*4 bytes), 4 passes from LDS
    size_t lds_bytes = (size_t)M * sizeof(unsigned);
    k_select<<<2, 1024, lds_bytes, stream>>>(tw, lossbuf, count, gmax_u, ep,
                                             ki, thr_u, cless, M);

    // weights + dot partials
    dim3 g4((M + 255) / 256, 2);
    k_weight<<<g4, 256, 0, stream>>>(tw, ul, lossbuf, gmax_u, outw, ki, thr_u,
                                     eqc, eqlist, acc, M, Kj);

    // tie fixup + final scalar
    k_fix<<<1, 256, 0, stream>>>(outw, out0, lossbuf, ki, cless, eqc, eqlist, acc, M, Kj);
}

// Round 8
// 204.655 us; speedup vs baseline: 1.4374x; 1.0177x over previous
//
#include <hip/hip_runtime.h>
#include <math.h>

#define EQCAP 2048
#define PI_D 3.141592653589793

// ---------- helpers ----------
__device__ inline float wred_max(float v) {
    #pragma unroll
    for (int o = 32; o; o >>= 1) v = fmaxf(v, __shfl_xor(v, o));
    return v;
}
__device__ inline float wred_sum(float v) {
    #pragma unroll
    for (int o = 32; o; o >>= 1) v += __shfl_xor(v, o);
    return v;
}
__device__ inline unsigned fflip(float f) {
    unsigned b = __float_as_uint(f);
    return (b & 0x80000000u) ? ~b : (b | 0x80000000u);
}

// ---------- kernel 0: zero the scalar workspace slots ----------
__global__ void k_init(double* acc, int* count, unsigned* gmax_u, int* eqc) {
    if (threadIdx.x == 0) {
        *acc = 0.0; *count = 0;
        gmax_u[0] = 0u; gmax_u[1] = 0u;
        eqc[0] = 0; eqc[1] = 0;
    }
}

// ---------- kernel 1: per-row KL loss (VALU-bound -> native exp/log) ----------
// R7 PMC: VALUBusy 60%, hbm 19% -> libm expf/logf dominated (~990 winst/row).
// __expf/__logf (v_exp_f32/v_log_f32) cut exp/log code ~8x; per-row loss error
// ~1e-10 (mean over 512 bins) vs ~6e-8 selection gap -> ranking stable.
__global__ __launch_bounds__(256) void k_loss(
    const float* __restrict__ px, const float* __restrict__ py,
    const float* __restrict__ gx, const float* __restrict__ gy,
    float* __restrict__ lossbuf, int M)
{
    int wid  = (blockIdx.x * blockDim.x + threadIdx.x) >> 6;
    int lane = threadIdx.x & 63;
    if (wid >= 2 * M) return;
    int ax  = wid >= M;
    int row = ax ? wid - M : wid;
    const float* p = ax ? py : px;
    const float* g = ax ? gy : gx;
    const float4* p4 = reinterpret_cast<const float4*>(p + (size_t)row * 512);
    const float4* g4 = reinterpret_cast<const float4*>(g + (size_t)row * 512);
    float4 pa = p4[lane], pb = p4[lane + 64];
    float4 ga = g4[lane], gb = g4[lane + 64];
    float pv[8] = {pa.x, pa.y, pa.z, pa.w, pb.x, pb.y, pb.z, pb.w};
    float gv[8] = {ga.x, ga.y, ga.z, ga.w, gb.x, gb.y, gb.z, gb.w};

    float mp = -INFINITY, mg = -INFINITY;
    #pragma unroll
    for (int i = 0; i < 8; i++) { mp = fmaxf(mp, pv[i]); mg = fmaxf(mg, gv[i]); }
    mp = wred_max(mp); mg = wred_max(mg);

    float sp = 0.f, sg = 0.f;
    #pragma unroll
    for (int i = 0; i < 8; i++) { sp += __expf(pv[i] - mp); sg += __expf(gv[i] - mg); }
    sp = wred_sum(sp); sg = wred_sum(sg);
    float lp = __logf(sp), lg = __logf(sg);

    float acc = 0.f;
    #pragma unroll
    for (int i = 0; i < 8; i++) {
        float lsg = (gv[i] - mg) - lg;      // log_softmax(gt)
        float lsp = (pv[i] - mp) - lp;      // log_softmax(pred)
        acc += __expf(lsg) * (lsg - lsp);
    }
    acc = wred_sum(acc);
    if (lane == 0) lossbuf[wid] = acc * (1.0f / 512.0f);
}

// ---------- kernel 2: multi-block stats: count_nonzero(tw), per-axis max ----------
__global__ __launch_bounds__(256) void k_stats2(
    const float* __restrict__ tw, const float* __restrict__ lossbuf,
    int* __restrict__ count, unsigned* __restrict__ gmax_u, int M)
{
    int tid = threadIdx.x, lane = tid & 63, wv = tid >> 6;
    int j = blockIdx.x * 256 + tid;
    int c = 0; unsigned ux = 0u, uy = 0u;
    if (j < M) {
        c  = (tw[j] != 0.0f);
        ux = fflip(lossbuf[j]);
        uy = fflip(lossbuf[M + j]);
    }
    #pragma unroll
    for (int o = 32; o; o >>= 1) {
        c += __shfl_xor(c, o);
        ux = max(ux, (unsigned)__shfl_xor((int)ux, o));
        uy = max(uy, (unsigned)__shfl_xor((int)uy, o));
    }
    __shared__ int sc[4]; __shared__ unsigned sx[4], sy[4];
    if (lane == 0) { sc[wv] = c; sx[wv] = ux; sy[wv] = uy; }
    __syncthreads();
    if (tid == 0) {
        int cs = sc[0] + sc[1] + sc[2] + sc[3];
        unsigned xs = max(max(sx[0], sx[1]), max(sx[2], sx[3]));
        unsigned ys = max(max(sy[0], sy[1]), max(sy[2], sy[3]));
        if (cs) atomicAdd(count, cs);
        atomicMax(&gmax_u[0], xs);
        atomicMax(&gmax_u[1], ys);
    }
}

// ---------- kernel 3: radix select — stage keys in LDS once, 4 passes from LDS ----------
// 1024 threads/block, one block per axis. Global data is touched exactly once.
__global__ __launch_bounds__(1024) void k_select(
    const float* __restrict__ tw, const float* __restrict__ lossbuf,
    const int* __restrict__ count, const unsigned* __restrict__ gmax_u,
    const int* __restrict__ ep,
    int* __restrict__ ki, unsigned* __restrict__ thr_u, int* __restrict__ cless, int M)
{
    extern __shared__ unsigned keys[];      // M unsigned keys (68 KB for M=17408)
    int ax = blockIdx.x;
    int tid = threadIdx.x, lane = tid & 63, wv = tid >> 6;
    __shared__ int hist[256];
    __shared__ unsigned s_pref;
    __shared__ int s_kr, s_cl;
    __shared__ int wsum[4];

    if (tid == 0) {
        int c = *count;
        double cur = fmin(fmax((double)(ep[0] - 210), 0.0), 30.0);
        double r = 0.5 * (cos(PI_D * cur / 30.0) + 1.0);
        r = fmin(fmax(r, 0.8), 1.0);
        int k = (int)((double)c * r);    // truncation matches Python int()
        s_kr = k; s_pref = 0u; s_cl = 0;
        if (ax == 0) *ki = k;
    }

    // stage keys: independent loads, fully pipelined; one global pass total
    unsigned gmu = gmax_u[ax];
    const float* lb = lossbuf + (size_t)ax * M;
    for (int j = tid; j < M; j += 1024) {
        float t = tw[j];
        float l = lb[j];
        keys[j] = (t > 0.f) ? fflip(l) : gmu;
    }
    __syncthreads();

    int k0 = s_kr;
    if (k0 <= 0) { if (tid == 0) { thr_u[ax] = 0u; cless[ax] = 0; } return; }

    const unsigned mhi[4] = {0x00000000u, 0xFF000000u, 0xFFFF0000u, 0xFFFFFF00u};

    for (int pass = 0; pass < 4; ++pass) {
        int shift = 24 - 8 * pass;
        if (tid < 256) hist[tid] = 0;
        __syncthreads();
        unsigned m = mhi[pass];
        unsigned pref = s_pref;
        for (int j = tid; j < M; j += 1024) {
            unsigned v = keys[j];
            if ((v & m) == (pref & m)) atomicAdd(&hist[(v >> shift) & 255], 1);
        }
        __syncthreads();
        int kr = s_kr;                 // read before anyone can write it
        int h = (tid < 256) ? hist[tid] : 0;
        int inc = h;
        #pragma unroll
        for (int o = 1; o < 64; o <<= 1) {
            int n = __shfl_up(inc, o);
            if (lane >= o) inc += n;
        }
        if (lane == 63 && wv < 4) wsum[wv] = inc;
        __syncthreads();               // separates s_kr read from the write below
        if (tid < 256) {
            int off = 0;
            #pragma unroll
            for (int w = 0; w < 4; w++) if (w < wv) off += wsum[w];
            int incl = inc + off, excl = incl - h;
            if (excl < kr && incl >= kr) { // exactly one thread
                s_pref |= ((unsigned)tid) << shift;
                s_kr = kr - excl;
                s_cl += excl;
            }
        }
        __syncthreads();
    }
    if (tid == 0) { thr_u[ax] = s_pref; cless[ax] = s_cl; }
}

// ---------- kernel 4: weights + masked dot partials ----------
__global__ __launch_bounds__(256) void k_weight(
    const float* __restrict__ tw, const int* __restrict__ ul,
    const float* __restrict__ lossbuf, const unsigned* __restrict__ gmax_u,
    float* __restrict__ outw, const int* __restrict__ ki,
    const unsigned* __restrict__ thr_u, int* __restrict__ eqc,
    int* __restrict__ eqlist, double* __restrict__ acc, int M, int Kj)
{
    int ax = blockIdx.y;
    int m = blockIdx.x * blockDim.x + threadIdx.x;
    double contrib = 0.0;
    if (m < M) {
        int k = *ki;
        float mask = 0.f;
        unsigned v = (tw[m] > 0.f) ? fflip(lossbuf[(size_t)ax * M + m]) : gmax_u[ax];
        unsigned t = thr_u[ax];
        if (k > 0) {
            if (v < t) mask = 1.f;
            else if (v == t) {
                int pos = atomicAdd(&eqc[ax], 1);
                if (pos < EQCAP) eqlist[ax * EQCAP + pos] = m;
            }
        }
        float wr = (ul[m / Kj] == 0) ? tw[m] : 0.f;   // weight_real
        float wall = 2.f * wr + mask;
        outw[(size_t)ax * M + m] = wall;
        contrib = (double)lossbuf[(size_t)ax * M + m] * (double)wall;
    }
    #pragma unroll
    for (int o = 32; o; o >>= 1) contrib += __shfl_xor(contrib, o);
    __shared__ double s_c[4];
    int lane = threadIdx.x & 63, wv = threadIdx.x >> 6;
    if (lane == 0) s_c[wv] = contrib;
    __syncthreads();
    if (threadIdx.x == 0) atomicAdd(acc, s_c[0] + s_c[1] + s_c[2] + s_c[3]);
}

// ---------- kernel 5: tie fixup (lowest-index semantics) + final scalar ----------
__global__ __launch_bounds__(256) void k_fix(
    float* __restrict__ outw, float* __restrict__ out0,
    const float* __restrict__ lossbuf, const int* __restrict__ ki,
    const int* __restrict__ cless, const int* __restrict__ eqc,
    const int* __restrict__ eqlist, const double* __restrict__ acc, int M, int Kj)
{
    __shared__ double s_c[4];
    int tid = threadIdx.x;
    double extra = 0.0;
    for (int ax = 0; ax < 2; ++ax) {
        int k = *ki;
        int ec = eqc[ax]; if (ec > EQCAP) ec = EQCAP;
        int need = (k > 0) ? (k - cless[ax]) : 0;
        if (need < 0) need = 0;
        if (need > ec) need = ec;
        if (need == ec) {
            for (int i = tid; i < ec; i += 256) {
                int m = eqlist[ax * EQCAP + i];
                outw[(size_t)ax * M + m] += 1.f;
                extra += (double)lossbuf[(size_t)ax * M + m];
            }
        } else if (tid == 0) {
            // pick `need` lowest indices among equals (top_k tie semantics)
            int last = -1;
            for (int s = 0; s < need; ++s) {
                int best = 0x7fffffff;
                for (int i = 0; i < ec; i++) {
                    int v = eqlist[ax * EQCAP + i];
                    if (v > last && v < best) best = v;
                }
                last = best;
                outw[(size_t)ax * M + best] += 1.f;
                extra += (double)lossbuf[(size_t)ax * M + best];
            }
        }
        __syncthreads();
    }
    #pragma unroll
    for (int o = 32; o; o >>= 1) extra += __shfl_xor(extra, o);
    int lane = tid & 63, wv = tid >> 6;
    if (lane == 0) s_c[wv] = extra;
    __syncthreads();
    if (tid == 0)
        out0[0] = (float)((acc[0] + s_c[0] + s_c[1] + s_c[2] + s_c[3]) / (double)Kj);
}

extern "C" void kernel_launch(void* const* d_in, const int* in_sizes, int n_in,
                              void* d_out, int out_size, void* d_ws, size_t ws_size,
                              hipStream_t stream)
{
    const float* px = (const float*)d_in[0];
    const float* py = (const float*)d_in[1];
    const float* gx = (const float*)d_in[2];
    const float* gy = (const float*)d_in[3];
    const float* tw = (const float*)d_in[4];
    const int*   ul = (const int*)d_in[5];
    const int*   ep = (const int*)d_in[6];

    int M  = in_sizes[4];        // N*K = 17408
    int N  = in_sizes[5];        // 1024
    int Kj = M / N;              // 17

    float* out  = (float*)d_out;
    float* out0 = out;           // scalar loss
    float* outw = out + 1;       // [2*M] weights (x then y)

    char* ws = (char*)d_ws;
    double*   acc     = (double*)(ws + 0);
    int*      ki      = (int*)(ws + 8);
    int*      count   = (int*)(ws + 12);
    unsigned* gmax_u  = (unsigned*)(ws + 16);
    unsigned* thr_u   = (unsigned*)(ws + 24);
    int*      cless   = (int*)(ws + 32);
    int*      eqc     = (int*)(ws + 40);
    float*    lossbuf = (float*)(ws + 64);
    int*      eqlist  = (int*)(ws + 64 + (size_t)8 * M);

    k_init<<<1, 64, 0, stream>>>(acc, count, gmax_u, eqc);

    // per-row losses (wave per row, 4 waves/block)
    int nwaves = 2 * M;
    k_loss<<<(nwaves + 3) / 4, 256, 0, stream>>>(px, py, gx, gy, lossbuf, M);

    // multi-block count + per-axis max
    k_stats2<<<(M + 255) / 256, 256, 0, stream>>>(tw, lossbuf, count, gmax_u, M);

    // radix select: stage keys in LDS (dynamic, M*4 bytes), 4 passes from LDS
    size_t lds_bytes = (size_t)M * sizeof(unsigned);
    k_select<<<2, 1024, lds_bytes, stream>>>(tw, lossbuf, count, gmax_u, ep,
                                             ki, thr_u, cless, M);

    // weights + dot partials
    dim3 g4((M + 255) / 256, 2);
    k_weight<<<g4, 256, 0, stream>>>(tw, ul, lossbuf, gmax_u, outw, ki, thr_u,
                                     eqc, eqlist, acc, M, Kj);

    // tie fixup + final scalar
    k_fix<<<1, 256, 0, stream>>>(outw, out0, lossbuf, ki, cless, eqc, eqlist, acc, M, Kj);
}